// Round 2
// baseline (258.707 us; speedup 1.0000x reference)
//
#include <hip/hip_runtime.h>
#include <math.h>

// KabschLoss: loss = mean( (xc @ R - yc)^2 ), R = U Vh from SVD of C = xc^T yc.
// Identity: sum |xc R - yc|^2 = Sx + Sy - 2*nuclear_norm(C)  (R orthogonal,
// tr(R^T C) = sum of singular values). Only per-batch raw moments and the
// singular values of the 3x3 covariance are needed (closed-form eig of C^T C).
//
// R1: 16 consecutive points per lane -> 12 aligned float4 loads per array
// (phase-0 component layout, no cross-lane fixup), __launch_bounds__(256,1)
// to lift the 60-VGPR cap that serialized loads in R0 (MLP-bound, 76 us).

#define NPTS 128

__device__ __forceinline__ float xsum(float v, int m) {
    return v + __shfl_xor(v, m);
}

__global__ __launch_bounds__(256, 1) void kabsch_kernel(
        const float* __restrict__ x, const float* __restrict__ y,
        float* __restrict__ out, float scale) {
    const int tid  = threadIdx.x;
    const int lane = tid & 63;
    const int wave = tid >> 6;
    const int g    = lane >> 3;   // group of 8 lanes -> one batch
    const int sub  = lane & 7;    // lane within group
    const int b    = blockIdx.x * 32 + wave * 8 + g;

    // Lane owns points [16*sub, 16*sub+16) -> floats [48*sub, 48*sub+48)
    // = 12 float4, 16-byte aligned (192 B per lane region).
    const float4* xq = (const float4*)(x + (size_t)b * (NPTS * 3) + sub * 48);
    const float4* yq = (const float4*)(y + (size_t)b * (NPTS * 3) + sub * 48);

    // 17 per-lane accumulators (raw moments)
    float sx0=0.f,sx1=0.f,sx2=0.f, sy0=0.f,sy1=0.f,sy2=0.f;
    float qx=0.f, qy=0.f;
    float c00=0.f,c01=0.f,c02=0.f,c10=0.f,c11=0.f,c12=0.f,c20=0.f,c21=0.f,c22=0.f;

    #pragma unroll
    for (int h = 0; h < 2; ++h) {
        // 12 independent dwordx4 loads in flight per half
        float4 xv0 = xq[6*h+0], xv1 = xq[6*h+1], xv2 = xq[6*h+2];
        float4 xv3 = xq[6*h+3], xv4 = xq[6*h+4], xv5 = xq[6*h+5];
        float4 yv0 = yq[6*h+0], yv1 = yq[6*h+1], yv2 = yq[6*h+2];
        float4 yv3 = yq[6*h+3], yv4 = yq[6*h+4], yv5 = yq[6*h+5];

        float fx[24], fy[24];
        fx[ 0]=xv0.x; fx[ 1]=xv0.y; fx[ 2]=xv0.z; fx[ 3]=xv0.w;
        fx[ 4]=xv1.x; fx[ 5]=xv1.y; fx[ 6]=xv1.z; fx[ 7]=xv1.w;
        fx[ 8]=xv2.x; fx[ 9]=xv2.y; fx[10]=xv2.z; fx[11]=xv2.w;
        fx[12]=xv3.x; fx[13]=xv3.y; fx[14]=xv3.z; fx[15]=xv3.w;
        fx[16]=xv4.x; fx[17]=xv4.y; fx[18]=xv4.z; fx[19]=xv4.w;
        fx[20]=xv5.x; fx[21]=xv5.y; fx[22]=xv5.z; fx[23]=xv5.w;
        fy[ 0]=yv0.x; fy[ 1]=yv0.y; fy[ 2]=yv0.z; fy[ 3]=yv0.w;
        fy[ 4]=yv1.x; fy[ 5]=yv1.y; fy[ 6]=yv1.z; fy[ 7]=yv1.w;
        fy[ 8]=yv2.x; fy[ 9]=yv2.y; fy[10]=yv2.z; fy[11]=yv2.w;
        fy[12]=yv3.x; fy[13]=yv3.y; fy[14]=yv3.z; fy[15]=yv3.w;
        fy[16]=yv4.x; fy[17]=yv4.y; fy[18]=yv4.z; fy[19]=yv4.w;
        fy[20]=yv5.x; fy[21]=yv5.y; fy[22]=yv5.z; fy[23]=yv5.w;

        #pragma unroll
        for (int p = 0; p < 8; ++p) {
            float px0=fx[3*p], px1=fx[3*p+1], px2=fx[3*p+2];
            float py0=fy[3*p], py1=fy[3*p+1], py2=fy[3*p+2];
            sx0+=px0; sx1+=px1; sx2+=px2;
            sy0+=py0; sy1+=py1; sy2+=py2;
            qx = fmaf(px0,px0,fmaf(px1,px1,fmaf(px2,px2,qx)));
            qy = fmaf(py0,py0,fmaf(py1,py1,fmaf(py2,py2,qy)));
            c00=fmaf(px0,py0,c00); c01=fmaf(px0,py1,c01); c02=fmaf(px0,py2,c02);
            c10=fmaf(px1,py0,c10); c11=fmaf(px1,py1,c11); c12=fmaf(px1,py2,c12);
            c20=fmaf(px2,py0,c20); c21=fmaf(px2,py1,c21); c22=fmaf(px2,py2,c22);
        }
    }

    // Butterfly reduce the 17 sums within each 8-lane group (masks 1,2,4).
    #pragma unroll
    for (int m = 1; m <= 4; m <<= 1) {
        sx0=xsum(sx0,m); sx1=xsum(sx1,m); sx2=xsum(sx2,m);
        sy0=xsum(sy0,m); sy1=xsum(sy1,m); sy2=xsum(sy2,m);
        qx =xsum(qx ,m); qy =xsum(qy ,m);
        c00=xsum(c00,m); c01=xsum(c01,m); c02=xsum(c02,m);
        c10=xsum(c10,m); c11=xsum(c11,m); c12=xsum(c12,m);
        c20=xsum(c20,m); c21=xsum(c21,m); c22=xsum(c22,m);
    }
    // Now every lane in a group holds its batch's full sums.

    const float invN = 1.0f / (float)NPTS;
    // Mean-centered covariance C = Sxy - sx sy^T / N
    float C00 = c00 - sx0*sy0*invN, C01 = c01 - sx0*sy1*invN, C02 = c02 - sx0*sy2*invN;
    float C10 = c10 - sx1*sy0*invN, C11 = c11 - sx1*sy1*invN, C12 = c12 - sx1*sy2*invN;
    float C20 = c20 - sx2*sy0*invN, C21 = c21 - sx2*sy1*invN, C22 = c22 - sx2*sy2*invN;
    float Sx = qx - (sx0*sx0 + sx1*sx1 + sx2*sx2) * invN;
    float Sy = qy - (sy0*sy0 + sy1*sy1 + sy2*sy2) * invN;

    // A = C^T C (symmetric PSD); closed-form eigenvalues (trigonometric).
    float a00 = C00*C00 + C10*C10 + C20*C20;
    float a01 = C00*C01 + C10*C11 + C20*C21;
    float a02 = C00*C02 + C10*C12 + C20*C22;
    float a11 = C01*C01 + C11*C11 + C21*C21;
    float a12 = C01*C02 + C11*C12 + C21*C22;
    float a22 = C02*C02 + C12*C12 + C22*C22;

    float q = (a00 + a11 + a22) * (1.0f / 3.0f);
    float b00 = a00 - q, b11 = a11 - q, b22 = a22 - q;
    float p2 = (b00*b00 + b11*b11 + b22*b22
                + 2.0f * (a01*a01 + a02*a02 + a12*a12)) * (1.0f / 6.0f);
    float p = sqrtf(fmaxf(p2, 0.0f));
    float detB = b00 * (b11*b22 - a12*a12)
               - a01 * (a01*b22 - a12*a02)
               + a02 * (a01*a12 - b11*a02);
    float p3 = p * p * p;
    float r = (p3 > 1e-30f) ? (0.5f * detB / p3) : 0.0f;
    r = fminf(1.0f, fmaxf(-1.0f, r));
    float phi = acosf(r) * (1.0f / 3.0f);
    float two_p = 2.0f * p;
    float l1 = q + two_p * cosf(phi);                        // largest
    float l3 = q + two_p * cosf(phi + 2.0943951023931953f);  // smallest
    float l2 = 3.0f * q - l1 - l3;
    float nuc = sqrtf(fmaxf(l1, 0.0f)) + sqrtf(fmaxf(l2, 0.0f)) + sqrtf(fmaxf(l3, 0.0f));

    float term = Sx + Sy - 2.0f * nuc;

    // Sum the 8 distinct group terms across the wave (masks 8,16,32).
    term += __shfl_xor(term, 8);
    term += __shfl_xor(term, 16);
    term += __shfl_xor(term, 32);

    __shared__ float wsum[4];
    if (lane == 0) wsum[wave] = term;
    __syncthreads();
    if (tid == 0) {
        float t = (wsum[0] + wsum[1] + wsum[2] + wsum[3]) * scale;
        atomicAdd(out, t);
    }
}

extern "C" void kernel_launch(void* const* d_in, const int* in_sizes, int n_in,
                              void* d_out, int out_size, void* d_ws, size_t ws_size,
                              hipStream_t stream) {
    const float* x = (const float*)d_in[0];
    const float* y = (const float*)d_in[1];
    float* out = (float*)d_out;

    const int B = in_sizes[0] / (NPTS * 3);   // 65536
    const float scale = 1.0f / ((float)B * (float)NPTS * 3.0f);

    hipMemsetAsync(out, 0, sizeof(float), stream);   // harness poisons d_out
    const int blocks = B / 32;                       // 32 batches per 256-thread block
    kabsch_kernel<<<blocks, 256, 0, stream>>>(x, y, out, scale);
}

// Round 3
// 215.256 us; speedup vs baseline: 1.2019x; 1.2019x over previous
//
#include <hip/hip_runtime.h>
#include <math.h>

// KabschLoss: loss = mean( (xc @ R - yc)^2 ), R = U Vh from SVD of C = xc^T yc.
// Identity: sum |xc R - yc|^2 = Sx + Sy - 2*nuclear_norm(C). Only per-batch raw
// moments + singular values of the 3x3 covariance needed (closed-form eig, exact
// vs harness: absmax 0.0 in R0/R1).
//
// R2: R1's lane-strided register loads over-fetched 1.8x (366 MB, L2 thrash) and
// the compiler serialized them (VGPR 32). Fix: coalesced global->LDS staging via
// global_load_lds width=16 (1 KB contiguous per wave-instr, async), strided
// reorganization happens in LDS where conflicts are ~free at this scale.
// 16 batches/block = 48 KB LDS -> 3 blocks/CU (12 waves/CU).

#define NPTS 128
#define BPB 16                 // batches per block
#define F4B 96                 // float4 per batch (384 floats)

__device__ __forceinline__ float xsum(float v, int m) {
    return v + __shfl_xor(v, m);
}

__global__ __launch_bounds__(256, 3) void kabsch_kernel(
        const float4* __restrict__ x4, const float4* __restrict__ y4,
        float* __restrict__ out, float scale) {
    __shared__ float4 smem[2 * BPB * F4B];   // 48 KB: x tiles then y tiles

    const int tid  = threadIdx.x;
    const int lane = tid & 63;
    const int wave = tid >> 6;

    const size_t blockBase = (size_t)blockIdx.x * (BPB * F4B);

    // ---- Stage: each wave copies 6 x-rows + 6 y-rows of 64 float4 (1 KB each),
    // fully coalesced, async into LDS.
    {
        const int rpw = (BPB * F4B) / (64 * 4);   // 6 rows per wave per array
        #pragma unroll
        for (int j = 0; j < rpw; ++j) {
            const int idx = (wave * rpw + j) * 64;   // float4 index in block chunk
#if defined(__has_builtin)
#if __has_builtin(__builtin_amdgcn_global_load_lds)
            __builtin_amdgcn_global_load_lds(
                (const __attribute__((address_space(1))) void*)(x4 + blockBase + idx + lane),
                (__attribute__((address_space(3))) void*)(&smem[idx]), 16, 0, 0);
            __builtin_amdgcn_global_load_lds(
                (const __attribute__((address_space(1))) void*)(y4 + blockBase + idx + lane),
                (__attribute__((address_space(3))) void*)(&smem[BPB * F4B + idx]), 16, 0, 0);
#else
            smem[idx + lane] = x4[blockBase + idx + lane];
            smem[BPB * F4B + idx + lane] = y4[blockBase + idx + lane];
#endif
#else
            smem[idx + lane] = x4[blockBase + idx + lane];
            smem[BPB * F4B + idx + lane] = y4[blockBase + idx + lane];
#endif
        }
    }
    __syncthreads();   // compiler emits vmcnt(0) drain for the async loads

    // ---- Compute: 16 lanes per batch, 8 points (24 floats = 6 float4) per lane.
    const int g    = lane >> 4;            // 4 batches per wave
    const int sub  = lane & 15;
    const int bblk = wave * 4 + g;
    const float4* xs = &smem[bblk * F4B + sub * 6];
    const float4* ys = &smem[BPB * F4B + bblk * F4B + sub * 6];

    float4 xv0 = xs[0], xv1 = xs[1], xv2 = xs[2], xv3 = xs[3], xv4 = xs[4], xv5 = xs[5];
    float4 yv0 = ys[0], yv1 = ys[1], yv2 = ys[2], yv3 = ys[3], yv4 = ys[4], yv5 = ys[5];

    float fx[24], fy[24];
    fx[ 0]=xv0.x; fx[ 1]=xv0.y; fx[ 2]=xv0.z; fx[ 3]=xv0.w;
    fx[ 4]=xv1.x; fx[ 5]=xv1.y; fx[ 6]=xv1.z; fx[ 7]=xv1.w;
    fx[ 8]=xv2.x; fx[ 9]=xv2.y; fx[10]=xv2.z; fx[11]=xv2.w;
    fx[12]=xv3.x; fx[13]=xv3.y; fx[14]=xv3.z; fx[15]=xv3.w;
    fx[16]=xv4.x; fx[17]=xv4.y; fx[18]=xv4.z; fx[19]=xv4.w;
    fx[20]=xv5.x; fx[21]=xv5.y; fx[22]=xv5.z; fx[23]=xv5.w;
    fy[ 0]=yv0.x; fy[ 1]=yv0.y; fy[ 2]=yv0.z; fy[ 3]=yv0.w;
    fy[ 4]=yv1.x; fy[ 5]=yv1.y; fy[ 6]=yv1.z; fy[ 7]=yv1.w;
    fy[ 8]=yv2.x; fy[ 9]=yv2.y; fy[10]=yv2.z; fy[11]=yv2.w;
    fy[12]=yv3.x; fy[13]=yv3.y; fy[14]=yv3.z; fy[15]=yv3.w;
    fy[16]=yv4.x; fy[17]=yv4.y; fy[18]=yv4.z; fy[19]=yv4.w;
    fy[20]=yv5.x; fy[21]=yv5.y; fy[22]=yv5.z; fy[23]=yv5.w;

    float sx0=0.f,sx1=0.f,sx2=0.f, sy0=0.f,sy1=0.f,sy2=0.f;
    float qx=0.f, qy=0.f;
    float c00=0.f,c01=0.f,c02=0.f,c10=0.f,c11=0.f,c12=0.f,c20=0.f,c21=0.f,c22=0.f;

    #pragma unroll
    for (int p = 0; p < 8; ++p) {
        float px0=fx[3*p], px1=fx[3*p+1], px2=fx[3*p+2];
        float py0=fy[3*p], py1=fy[3*p+1], py2=fy[3*p+2];
        sx0+=px0; sx1+=px1; sx2+=px2;
        sy0+=py0; sy1+=py1; sy2+=py2;
        qx = fmaf(px0,px0,fmaf(px1,px1,fmaf(px2,px2,qx)));
        qy = fmaf(py0,py0,fmaf(py1,py1,fmaf(py2,py2,qy)));
        c00=fmaf(px0,py0,c00); c01=fmaf(px0,py1,c01); c02=fmaf(px0,py2,c02);
        c10=fmaf(px1,py0,c10); c11=fmaf(px1,py1,c11); c12=fmaf(px1,py2,c12);
        c20=fmaf(px2,py0,c20); c21=fmaf(px2,py1,c21); c22=fmaf(px2,py2,c22);
    }

    // Butterfly reduce the 17 sums within each 16-lane group (masks 1,2,4,8).
    #pragma unroll
    for (int m = 1; m <= 8; m <<= 1) {
        sx0=xsum(sx0,m); sx1=xsum(sx1,m); sx2=xsum(sx2,m);
        sy0=xsum(sy0,m); sy1=xsum(sy1,m); sy2=xsum(sy2,m);
        qx =xsum(qx ,m); qy =xsum(qy ,m);
        c00=xsum(c00,m); c01=xsum(c01,m); c02=xsum(c02,m);
        c10=xsum(c10,m); c11=xsum(c11,m); c12=xsum(c12,m);
        c20=xsum(c20,m); c21=xsum(c21,m); c22=xsum(c22,m);
    }

    const float invN = 1.0f / (float)NPTS;
    float C00 = c00 - sx0*sy0*invN, C01 = c01 - sx0*sy1*invN, C02 = c02 - sx0*sy2*invN;
    float C10 = c10 - sx1*sy0*invN, C11 = c11 - sx1*sy1*invN, C12 = c12 - sx1*sy2*invN;
    float C20 = c20 - sx2*sy0*invN, C21 = c21 - sx2*sy1*invN, C22 = c22 - sx2*sy2*invN;
    float Sx = qx - (sx0*sx0 + sx1*sx1 + sx2*sx2) * invN;
    float Sy = qy - (sy0*sy0 + sy1*sy1 + sy2*sy2) * invN;

    // A = C^T C; closed-form eigenvalues (trigonometric), nuclear norm of C.
    float a00 = C00*C00 + C10*C10 + C20*C20;
    float a01 = C00*C01 + C10*C11 + C20*C21;
    float a02 = C00*C02 + C10*C12 + C20*C22;
    float a11 = C01*C01 + C11*C11 + C21*C21;
    float a12 = C01*C02 + C11*C12 + C21*C22;
    float a22 = C02*C02 + C12*C12 + C22*C22;

    float q = (a00 + a11 + a22) * (1.0f / 3.0f);
    float b00 = a00 - q, b11 = a11 - q, b22 = a22 - q;
    float p2 = (b00*b00 + b11*b11 + b22*b22
                + 2.0f * (a01*a01 + a02*a02 + a12*a12)) * (1.0f / 6.0f);
    float p = sqrtf(fmaxf(p2, 0.0f));
    float detB = b00 * (b11*b22 - a12*a12)
               - a01 * (a01*b22 - a12*a02)
               + a02 * (a01*a12 - b11*a02);
    float p3 = p * p * p;
    float r = (p3 > 1e-30f) ? (0.5f * detB / p3) : 0.0f;
    r = fminf(1.0f, fmaxf(-1.0f, r));
    float phi = acosf(r) * (1.0f / 3.0f);
    float two_p = 2.0f * p;
    float l1 = q + two_p * cosf(phi);
    float l3 = q + two_p * cosf(phi + 2.0943951023931953f);
    float l2 = 3.0f * q - l1 - l3;
    float nuc = sqrtf(fmaxf(l1, 0.0f)) + sqrtf(fmaxf(l2, 0.0f)) + sqrtf(fmaxf(l3, 0.0f));

    float term = Sx + Sy - 2.0f * nuc;

    // Sum the wave's 4 distinct batch terms (masks 16, 32).
    term += __shfl_xor(term, 16);
    term += __shfl_xor(term, 32);

    __shared__ float wsum[4];
    if (lane == 0) wsum[wave] = term;
    __syncthreads();
    if (tid == 0) {
        float t = (wsum[0] + wsum[1] + wsum[2] + wsum[3]) * scale;
        atomicAdd(out, t);
    }
}

extern "C" void kernel_launch(void* const* d_in, const int* in_sizes, int n_in,
                              void* d_out, int out_size, void* d_ws, size_t ws_size,
                              hipStream_t stream) {
    const float4* x4 = (const float4*)d_in[0];
    const float4* y4 = (const float4*)d_in[1];
    float* out = (float*)d_out;

    const int B = in_sizes[0] / (NPTS * 3);   // 65536
    const float scale = 1.0f / ((float)B * (float)NPTS * 3.0f);

    hipMemsetAsync(out, 0, sizeof(float), stream);   // harness poisons d_out
    const int blocks = B / BPB;                      // 4096 blocks
    kabsch_kernel<<<blocks, 256, 0, stream>>>(x4, y4, out, scale);
}